// Round 6
// baseline (585.360 us; speedup 1.0000x reference)
//
#include <hip/hip_runtime.h>
#include <hip/hip_bf16.h>
#include <hip/hip_fp16.h>
#include <hip/hip_cooperative_groups.h>

namespace cg = cooperative_groups;

// Problem constants (match reference)
#define CUTOFF_C    12.0f
#define CUTOFF_SR_C 2.0f
#define CUTOFF_SQ_C 144.0f
#define KEHALF_C    7.199822675975274f

#define BLK1   1024
// vw-scatter: CH*4 = 80000 B LDS -> 2 blocks/CU (160000 <= 163840). nch=5 @100K.
#define CH_REC 20000

__device__ __forceinline__ float edge_energy(float d, float qi, float qj,
                                             float di, float dj) {
    float inv_d   = __frcp_rn(d);
    float dsh     = __fsqrt_rn(fmaf(d, d, 1.0f));
    float inv_dsh = __frcp_rn(dsh);
    float x  = d * (1.0f / CUTOFF_SR_C);
    float x3 = x * x * x;
    float sw = fmaf(x3, fmaf(x, fmaf(x, -6.0f, 15.0f), -10.0f), 1.0f);
    float sw_off = (d < CUTOFF_SR_C) ? sw : 0.0f;
    float Eoq = inv_d   + fmaf(d,   (1.0f / CUTOFF_SQ_C), -(2.0f / CUTOFF_C));
    float Esq = inv_dsh + fmaf(dsh, (1.0f / CUTOFF_SQ_C), -(2.0f / CUTOFF_C));
    float Eq  = (KEHALF_C * qi * qj) * fmaf(sw_off, Esq - Eoq, Eoq);
    float Eod = inv_d * inv_d * inv_d;
    float Esd = inv_dsh * inv_dsh * inv_dsh;
    float Ed  = (KEHALF_C * di * dj) * fmaf(sw_off, Esd - Eod, Eod);
    return Eq + Ed;
}

__device__ __forceinline__ unsigned h2bits(__half2 h) {
    union { __half2 h; unsigned u; } c; c.h = h; return c.u;
}
__device__ __forceinline__ __half2 bits2h(unsigned u) {
    union { unsigned u; __half2 h; } c; c.u = u; return c.h;
}
// half2 atomic add (LDS): HW atomicAdd(__half2*) (ds_pk_add_f16) if available.
template <typename T>
__device__ __forceinline__ auto atom_add_h2(T* p, T v, int)
    -> decltype(atomicAdd(p, v), void()) {
    atomicAdd(p, v);
}
template <typename T>
__device__ __forceinline__ void atom_add_h2(T* p, T v, long) {
    unsigned* u = (unsigned*)p;
    unsigned old = *u, assumed;
    do {
        assumed = old;
        __half2 sum = __hadd2(bits2h(assumed), v);
        old = atomicCAS(u, assumed, h2bits(sum));
    } while (old != assumed);
}

// Fast-exact per-edge radial factors via HW rcp/rsq (errors << fp16 rounding).
// Returns half2{qj*F, dipj*G} bit-pattern. Validity (d<=cutoff) handled by caller.
__device__ __forceinline__ unsigned vw_bits(float d, unsigned hqbits) {
    float inv_d   = __builtin_amdgcn_rcpf(d);
    float dsh2    = fmaf(d, d, 1.0f);
    float inv_dsh = __builtin_amdgcn_rsqf(dsh2);   // 1/sqrt(d^2+1)
    float dsh     = dsh2 * inv_dsh;                // sqrt(d^2+1)
    float x  = d * (1.0f / CUTOFF_SR_C);
    float x3 = x * x * x;
    float sw = fmaf(x3, fmaf(x, fmaf(x, -6.0f, 15.0f), -10.0f), 1.0f);
    float sw_off = (d < CUTOFF_SR_C) ? sw : 0.0f;
    float Foq = inv_d   + fmaf(d,   (1.0f / CUTOFF_SQ_C), -(2.0f / CUTOFF_C));
    float Fsq = inv_dsh + fmaf(dsh, (1.0f / CUTOFF_SQ_C), -(2.0f / CUTOFF_C));
    float F   = fmaf(sw_off, Fsq - Foq, Foq);
    float God = inv_d * inv_d * inv_d;
    float Gsd = inv_dsh * inv_dsh * inv_dsh;
    float G   = fmaf(sw_off, Gsd - God, God);
    float2 q2 = __half22float2(bits2h(hqbits));
    __half2 vw = __floats2half2_rn((KEHALF_C * q2.x) * F, (KEHALF_C * q2.y) * G);
    return h2bits(vw);
}

// =================== COOPERATIVE MEGA-KERNEL ===================
// R5 post-mortem: per-kernel work is at a practical floor (~85us), but
// ~35-40us of the 162us budget is inter-dispatch launch gaps (~8-11us per
// boundary). Fuse pack -> edge-vw -> LDS scatter -> reduce into ONE
// cooperative kernel with grid.sync() between phases: 5 dispatches -> 2.
// Phases are verbatim ports of the proven standalone kernels.
__global__ __launch_bounds__(BLK1, 8) void pc_mega(
    const float*   __restrict__ q,
    const float*   __restrict__ dip,
    const float*   __restrict__ dist,
    const int*     __restrict__ idx_i,
    const int*     __restrict__ idx_j,
    __half2*       __restrict__ qd,        // ws: [n_atoms]
    unsigned*      __restrict__ vw,        // ws: [n_edges]
    __half2*       __restrict__ partial,   // ws: [S][n_atoms]
    float*         __restrict__ out,
    int n_edges, int n4, int half, int n_atoms, int S, int gps, int nch)
{
    extern __shared__ char smem[];
    __half2* acc2 = (__half2*)smem;                        // CH_REC entries
    cg::grid_group grid = cg::this_grid();

    const int tid = (int)threadIdx.x;
    const int bid = (int)blockIdx.x;
    const int gt  = bid * BLK1 + tid;
    const int GT  = (int)gridDim.x * BLK1;

    // ---- Phase 0: pack {q,dip} -> half2 gather table ----
    for (int a = gt; a < n_atoms; a += GT)
        qd[a] = __floats2half2_rn(q[a], dip[a]);

    __threadfence();
    grid.sync();

    // ---- Phase A: per-edge vw (2-group batch, grid-stride) ----
    {
        const int4*   j4p = (const int4*)idx_j;
        const float4* d4p = (const float4*)dist;
        uint4* vwo = (uint4*)vw;

        for (int t = gt; t < half; t += GT) {
            const int  ga = t;
            const int  gb = t + half;
            const bool vb = gb < n4;
            const int  gbs = vb ? gb : ga;    // safe addr, cndmask not branch

            int4   ja = j4p[ga];
            int4   jb = j4p[gbs];
            float4 da = d4p[ga];
            float4 db = d4p[gbs];

            __half2 q0 = qd[ja.x], q1 = qd[ja.y], q2 = qd[ja.z], q3 = qd[ja.w];
            __half2 q4 = qd[jb.x], q5 = qd[jb.y], q6 = qd[jb.z], q7 = qd[jb.w];

            unsigned w0 = vw_bits(da.x, h2bits(q0));
            unsigned w1 = vw_bits(da.y, h2bits(q1));
            unsigned w2 = vw_bits(da.z, h2bits(q2));
            unsigned w3 = vw_bits(da.w, h2bits(q3));
            unsigned w4 = vw_bits(db.x, h2bits(q4));
            unsigned w5 = vw_bits(db.y, h2bits(q5));
            unsigned w6 = vw_bits(db.z, h2bits(q6));
            unsigned w7 = vw_bits(db.w, h2bits(q7));

            w0 = (da.x <= CUTOFF_C) ? w0 : 0u;
            w1 = (da.y <= CUTOFF_C) ? w1 : 0u;
            w2 = (da.z <= CUTOFF_C) ? w2 : 0u;
            w3 = (da.w <= CUTOFF_C) ? w3 : 0u;
            w4 = (db.x <= CUTOFF_C) ? w4 : 0u;
            w5 = (db.y <= CUTOFF_C) ? w5 : 0u;
            w6 = (db.z <= CUTOFF_C) ? w6 : 0u;
            w7 = (db.w <= CUTOFF_C) ? w7 : 0u;

            vwo[ga] = make_uint4(w0, w1, w2, w3);
            if (vb) vwo[gb] = make_uint4(w4, w5, w6, w7);
        }

        // scalar tail (n_edges % 4)
        const int tl = n_edges & 3;
        if (gt < tl) {
            int e = (n4 << 2) + gt;
            float d = dist[e];
            unsigned w = vw_bits(d, h2bits(qd[idx_j[e]]));
            vw[e] = (d <= CUTOFF_C) ? w : 0u;
        }
    }

    __threadfence();
    grid.sync();

    // ---- Phase B: chunked-LDS scatter (8-edge unrolled) ----
    if (bid < S * nch) {
        const int s = bid % S;
        const int c = bid / S;
        const unsigned base = (unsigned)(c * CH_REC);
        const int lim = min(CH_REC, n_atoms - (int)base);

        const __half2 hzero = __floats2half2_rn(0.0f, 0.0f);
        for (int i = tid; i < CH_REC; i += BLK1) acc2[i] = hzero;
        __syncthreads();

        const int4*  i4p = (const int4*)idx_i;
        const uint4* v4p = (const uint4*)vw;
        const int g0 = s * gps;
        const int g1 = min(g0 + gps, n4);
        for (int g = g0 + tid; g < g1; g += 2 * BLK1) {
            const int  gB   = g + BLK1;
            const bool hasB = gB < g1;
            const int  gBs  = hasB ? gB : g;

            int4  iA = i4p[g];
            int4  iB = i4p[gBs];
            uint4 vA = v4p[g];
            uint4 vB = v4p[gBs];

            unsigned a0 = (unsigned)iA.x - base;
            unsigned a1 = (unsigned)iA.y - base;
            unsigned a2 = (unsigned)iA.z - base;
            unsigned a3 = (unsigned)iA.w - base;
            if (a0 < (unsigned)CH_REC) atom_add_h2(&acc2[a0], bits2h(vA.x), 0);
            if (a1 < (unsigned)CH_REC) atom_add_h2(&acc2[a1], bits2h(vA.y), 0);
            if (a2 < (unsigned)CH_REC) atom_add_h2(&acc2[a2], bits2h(vA.z), 0);
            if (a3 < (unsigned)CH_REC) atom_add_h2(&acc2[a3], bits2h(vA.w), 0);
            if (hasB) {
                unsigned b0 = (unsigned)iB.x - base;
                unsigned b1 = (unsigned)iB.y - base;
                unsigned b2 = (unsigned)iB.z - base;
                unsigned b3 = (unsigned)iB.w - base;
                if (b0 < (unsigned)CH_REC) atom_add_h2(&acc2[b0], bits2h(vB.x), 0);
                if (b1 < (unsigned)CH_REC) atom_add_h2(&acc2[b1], bits2h(vB.y), 0);
                if (b2 < (unsigned)CH_REC) atom_add_h2(&acc2[b2], bits2h(vB.z), 0);
                if (b3 < (unsigned)CH_REC) atom_add_h2(&acc2[b3], bits2h(vB.w), 0);
            }
        }

        if (s == S - 1) {  // scalar tail edges
            for (int e = (n4 << 2) + tid; e < n_edges; e += BLK1) {
                unsigned lc = (unsigned)idx_i[e] - base;
                if (lc < (unsigned)CH_REC) atom_add_h2(&acc2[lc], bits2h(vw[e]), 0);
            }
        }

        __syncthreads();
        __half2* row = partial + (size_t)s * n_atoms + (int)base;
        for (int i = tid; i < lim; i += BLK1) row[i] = acc2[i];
    }

    __threadfence();
    grid.sync();

    // ---- Phase C: fp32 recombination out[a] = q[a]*sum(v) + dip[a]*sum(w) ----
    for (int a = gt; a < n_atoms; a += GT) {
        const __half2* p = partial + a;
        float sv = 0.0f, sw = 0.0f;
        #pragma unroll 4
        for (int s2 = 0; s2 < S; ++s2) {
            float2 t2 = __half22float2(p[(size_t)s2 * n_atoms]);
            sv += t2.x; sw += t2.y;
        }
        out[a] = fmaf(q[a], sv, dip[a] * sw);
    }
}

// =================== FALLBACK 4-KERNEL PATH (proven, 162us) ===================

__global__ __launch_bounds__(256) void pc_pack_qd_h(
    const float* __restrict__ q,
    const float* __restrict__ dip,
    __half2*     __restrict__ qd,
    int n_atoms)
{
    int a = blockIdx.x * 256 + threadIdx.x;
    if (a < n_atoms) qd[a] = __floats2half2_rn(q[a], dip[a]);
}

__global__ __launch_bounds__(256) void pc_edge_vw(
    const float*   __restrict__ dist,
    const int*     __restrict__ idx_j,
    const __half2* __restrict__ qd,
    uint4*         __restrict__ vwo,
    unsigned*      __restrict__ vws,
    int n_edges, int n4, int half)
{
    const int t = blockIdx.x * 256 + (int)threadIdx.x;
    const int4*   j4p = (const int4*)idx_j;
    const float4* d4p = (const float4*)dist;

    if (t < half) {
        const int  ga = t;
        const int  gb = t + half;
        const bool vb = gb < n4;
        const int  gbs = vb ? gb : ga;

        int4   ja = j4p[ga];
        int4   jb = j4p[gbs];
        float4 da = d4p[ga];
        float4 db = d4p[gbs];

        __half2 q0 = qd[ja.x], q1 = qd[ja.y], q2 = qd[ja.z], q3 = qd[ja.w];
        __half2 q4 = qd[jb.x], q5 = qd[jb.y], q6 = qd[jb.z], q7 = qd[jb.w];

        unsigned w0 = vw_bits(da.x, h2bits(q0));
        unsigned w1 = vw_bits(da.y, h2bits(q1));
        unsigned w2 = vw_bits(da.z, h2bits(q2));
        unsigned w3 = vw_bits(da.w, h2bits(q3));
        unsigned w4 = vw_bits(db.x, h2bits(q4));
        unsigned w5 = vw_bits(db.y, h2bits(q5));
        unsigned w6 = vw_bits(db.z, h2bits(q6));
        unsigned w7 = vw_bits(db.w, h2bits(q7));

        w0 = (da.x <= CUTOFF_C) ? w0 : 0u;
        w1 = (da.y <= CUTOFF_C) ? w1 : 0u;
        w2 = (da.z <= CUTOFF_C) ? w2 : 0u;
        w3 = (da.w <= CUTOFF_C) ? w3 : 0u;
        w4 = (db.x <= CUTOFF_C) ? w4 : 0u;
        w5 = (db.y <= CUTOFF_C) ? w5 : 0u;
        w6 = (db.z <= CUTOFF_C) ? w6 : 0u;
        w7 = (db.w <= CUTOFF_C) ? w7 : 0u;

        vwo[ga] = make_uint4(w0, w1, w2, w3);
        if (vb) vwo[gb] = make_uint4(w4, w5, w6, w7);
    }

    const int tl = n_edges & 3;
    if (blockIdx.x == 0 && (int)threadIdx.x < tl) {
        int e = (n4 << 2) + (int)threadIdx.x;
        float d = dist[e];
        unsigned w = vw_bits(d, h2bits(qd[idx_j[e]]));
        vws[e] = (d <= CUTOFF_C) ? w : 0u;
    }
}

template <int CH, int BLK>
__global__ __launch_bounds__(BLK) void pc_scatter_vw(
    const int*      __restrict__ idx_i,
    const unsigned* __restrict__ vw,
    __half2*        __restrict__ partial,
    int n_edges, int n4, int S, int gps, int n_atoms)
{
    extern __shared__ char smem[];
    __half2* acc2 = (__half2*)smem;

    const int s = blockIdx.x % S;
    const int c = blockIdx.x / S;
    const unsigned base = (unsigned)(c * CH);
    const int lim = min(CH, n_atoms - (int)base);

    const __half2 hzero = __floats2half2_rn(0.0f, 0.0f);
    for (int i = threadIdx.x; i < CH; i += BLK) acc2[i] = hzero;
    __syncthreads();

    const int4*  i4p = (const int4*)idx_i;
    const uint4* v4p = (const uint4*)vw;
    const int g0 = s * gps;
    const int g1 = min(g0 + gps, n4);
    for (int g = g0 + (int)threadIdx.x; g < g1; g += 2 * BLK) {
        const int  gB   = g + BLK;
        const bool hasB = gB < g1;
        const int  gBs  = hasB ? gB : g;

        int4  iA = i4p[g];
        int4  iB = i4p[gBs];
        uint4 vA = v4p[g];
        uint4 vB = v4p[gBs];

        unsigned a0 = (unsigned)iA.x - base;
        unsigned a1 = (unsigned)iA.y - base;
        unsigned a2 = (unsigned)iA.z - base;
        unsigned a3 = (unsigned)iA.w - base;
        if (a0 < (unsigned)CH) atom_add_h2(&acc2[a0], bits2h(vA.x), 0);
        if (a1 < (unsigned)CH) atom_add_h2(&acc2[a1], bits2h(vA.y), 0);
        if (a2 < (unsigned)CH) atom_add_h2(&acc2[a2], bits2h(vA.z), 0);
        if (a3 < (unsigned)CH) atom_add_h2(&acc2[a3], bits2h(vA.w), 0);
        if (hasB) {
            unsigned b0 = (unsigned)iB.x - base;
            unsigned b1 = (unsigned)iB.y - base;
            unsigned b2 = (unsigned)iB.z - base;
            unsigned b3 = (unsigned)iB.w - base;
            if (b0 < (unsigned)CH) atom_add_h2(&acc2[b0], bits2h(vB.x), 0);
            if (b1 < (unsigned)CH) atom_add_h2(&acc2[b1], bits2h(vB.y), 0);
            if (b2 < (unsigned)CH) atom_add_h2(&acc2[b2], bits2h(vB.z), 0);
            if (b3 < (unsigned)CH) atom_add_h2(&acc2[b3], bits2h(vB.w), 0);
        }
    }

    if (s == S - 1) {
        for (int e = (n4 << 2) + (int)threadIdx.x; e < n_edges; e += BLK) {
            unsigned lc = (unsigned)idx_i[e] - base;
            if (lc < (unsigned)CH) atom_add_h2(&acc2[lc], bits2h(vw[e]), 0);
        }
    }

    __syncthreads();
    __half2* row = partial + (size_t)s * n_atoms + (int)base;
    for (int i = threadIdx.x; i < lim; i += BLK) row[i] = acc2[i];
}

__global__ __launch_bounds__(256) void pc_reduce_vw(
    const __half2* __restrict__ partial,
    const float*   __restrict__ q,
    const float*   __restrict__ dip,
    float*         __restrict__ out,
    int n_atoms, int S)
{
    __shared__ float2 sh[256];
    int a0   = blockIdx.x * 64;
    int lane = threadIdx.x & 63;
    int w    = threadIdx.x >> 6;
    int a    = a0 + lane;

    float sv = 0.0f, sw = 0.0f;
    if (a < n_atoms) {
        int per = S >> 2;
        const __half2* p = partial + a;
        int s = w * per, send = s + per;
        for (; s < send; ++s) {
            float2 t = __half22float2(p[(size_t)s * n_atoms]);
            sv += t.x; sw += t.y;
        }
    }
    sh[threadIdx.x] = make_float2(sv, sw);
    __syncthreads();
    if (w == 0 && a < n_atoms) {
        float2 t0 = sh[lane],       t1 = sh[64 + lane];
        float2 t2 = sh[128 + lane], t3 = sh[192 + lane];
        float fv = (t0.x + t1.x) + (t2.x + t3.x);
        float fw = (t0.y + t1.y) + (t2.y + t3.y);
        out[a] = fmaf(q[a], fv, dip[a] * fw);
    }
}

__global__ __launch_bounds__(256) void pc_dipole_edges_atomic(
    const float* __restrict__ q,
    const float* __restrict__ dip,
    const float* __restrict__ dist,
    const int*   __restrict__ idx_i,
    const int*   __restrict__ idx_j,
    float*       __restrict__ out,
    int n_edges)
{
    int t = blockIdx.x * blockDim.x + threadIdx.x;
    const int stride = gridDim.x * blockDim.x;
    for (int e = t; e < n_edges; e += stride) {
        float d = dist[e];
        if (d > CUTOFF_C) continue;
        int i = idx_i[e], j = idx_j[e];
        atomicAdd(&out[i], edge_energy(d, q[i], q[j], dip[i], dip[j]));
    }
}

static int probe_blocks(const void* f, int blk, size_t lds) {
    hipError_t e1 = hipFuncSetAttribute(
        f, hipFuncAttributeMaxDynamicSharedMemorySize, (int)lds);
    int nb = 0;
    hipError_t e2 = hipOccupancyMaxActiveBlocksPerMultiprocessor(&nb, f, blk, lds);
    if (e1 != hipSuccess || e2 != hipSuccess) return 0;
    return nb;
}

extern "C" void kernel_launch(void* const* d_in, const int* in_sizes, int n_in,
                              void* d_out, int out_size, void* d_ws, size_t ws_size,
                              hipStream_t stream) {
    const float* q     = (const float*)d_in[0];
    const float* dip   = (const float*)d_in[1];
    const float* dist  = (const float*)d_in[2];
    const int*   idx_i = (const int*)d_in[3];
    const int*   idx_j = (const int*)d_in[4];
    float*       out   = (float*)d_out;

    int n_edges = in_sizes[2];
    int n_atoms = out_size;
    int n4      = n_edges >> 2;
    int half    = (n4 + 1) >> 1;

    size_t qd_b    = ((size_t)n_atoms * sizeof(__half2) + 255) & ~(size_t)255;
    size_t vw_b    = (((size_t)n_edges * 4) + 255) & ~(size_t)255;
    size_t lds_rec = (size_t)CH_REC * sizeof(__half2);               // 80000 B

    int nch = (n_atoms > 0) ? (n_atoms + CH_REC - 1) / CH_REC : 0;   // 5 @100K

    // ---------- Path 1: cooperative mega-kernel (2 dispatches total) ----------
    int dev = 0;
    (void)hipGetDevice(&dev);
    int coop_ok = 0, num_cu = 0;
    (void)hipDeviceGetAttribute(&coop_ok, hipDeviceAttributeCooperativeLaunch, dev);
    (void)hipDeviceGetAttribute(&num_cu, hipDeviceAttributeMultiprocessorCount, dev);

    if (coop_ok && num_cu > 0 && n_atoms > 0 && n4 > 0 &&
        ws_size > qd_b + vw_b) {
        int nb_mega = probe_blocks((const void*)&pc_mega, BLK1, lds_rec);
        if (nb_mega >= 1) {
            int blocks_per_cu = (nb_mega >= 2) ? 2 : 1;
            int grid = num_cu * blocks_per_cu;                       // 512 @MI355X

            int S_new = (grid / nch) & ~7;                           // 96
            size_t avail = ws_size - qd_b - vw_b;
            int S_fit = (int)(avail / ((size_t)n_atoms * sizeof(__half2))) & ~7;
            if (S_fit < S_new) S_new = S_fit;

            if (S_new >= 8) {
                __half2*  qd      = (__half2*)d_ws;
                unsigned* vw      = (unsigned*)((char*)d_ws + qd_b);
                __half2*  partial = (__half2*)((char*)d_ws + qd_b + vw_b);
                int       gps     = (n4 + S_new - 1) / S_new;

                void* args[] = {
                    (void*)&q, (void*)&dip, (void*)&dist,
                    (void*)&idx_i, (void*)&idx_j,
                    (void*)&qd, (void*)&vw, (void*)&partial, (void*)&out,
                    (void*)&n_edges, (void*)&n4, (void*)&half, (void*)&n_atoms,
                    (void*)&S_new, (void*)&gps, (void*)&nch };
                hipError_t le = hipLaunchCooperativeKernel(
                    (const void*)&pc_mega, dim3(grid), dim3(BLK1),
                    args, (unsigned)lds_rec, stream);
                if (le == hipSuccess) return;
                // else fall through to the 4-kernel path
            }
        }
    }

    // ---------- Path 2: proven 4-kernel vw path ----------
    int nb_rec = probe_blocks((const void*)&pc_scatter_vw<CH_REC, BLK1>,
                              BLK1, lds_rec);
    int S_new = 0;
    if (nb_rec >= 2 && n_atoms > 0 && n4 > 0 && ws_size > qd_b + vw_b) {
        int cap = 512;
        S_new = (cap / nch) & ~7;
        size_t avail = ws_size - qd_b - vw_b;
        int S_fit = (int)(avail / ((size_t)n_atoms * sizeof(__half2))) & ~7;
        if (S_fit < S_new) S_new = S_fit;
    }

    if (S_new >= 8) {
        __half2*  qd      = (__half2*)d_ws;
        unsigned* vw      = (unsigned*)((char*)d_ws + qd_b);
        __half2*  partial = (__half2*)((char*)d_ws + qd_b + vw_b);
        int       gps     = (n4 + S_new - 1) / S_new;
        int       gridA   = (half + 255) / 256;
        if (gridA < 1) gridA = 1;

        pc_pack_qd_h<<<(n_atoms + 255) / 256, 256, 0, stream>>>(q, dip, qd,
                                                                n_atoms);
        pc_edge_vw<<<gridA, 256, 0, stream>>>(dist, idx_j, qd,
                                              (uint4*)vw, vw,
                                              n_edges, n4, half);
        pc_scatter_vw<CH_REC, BLK1>
            <<<S_new * nch, BLK1, lds_rec, stream>>>(
                idx_i, vw, partial, n_edges, n4, S_new, gps, n_atoms);
        pc_reduce_vw<<<(n_atoms + 63) / 64, 256, 0, stream>>>(
            partial, q, dip, out, n_atoms, S_new);
        return;
    }

    // ---------- Path 3: full-precision atomic fallback ----------
    hipMemsetAsync(out, 0, (size_t)n_atoms * sizeof(float), stream);
    int grid = (n_edges + 255) / 256;
    if (grid < 1) grid = 1;
    pc_dipole_edges_atomic<<<grid, 256, 0, stream>>>(
        q, dip, dist, idx_i, idx_j, out, n_edges);
}

// Round 7
// 168.058 us; speedup vs baseline: 3.4831x; 3.4831x over previous
//
#include <hip/hip_runtime.h>
#include <hip/hip_bf16.h>
#include <hip/hip_fp16.h>

// Problem constants (match reference)
#define CUTOFF_C    12.0f
#define CUTOFF_SR_C 2.0f
#define CUTOFF_SQ_C 144.0f
#define KEHALF_C    7.199822675975274f

#define BLK1   1024

// Scatter configs: CH atoms of half2 accumulator in LDS.
// SOLO: 40000*4 = 160000 B, 1 block/CU, nch=3 @100K -> 19.2M visits.
// DUO : 20000*4 =  80000 B, 2 blocks/CU, nch=5 @100K -> 32M visits (fallback).
#define CH_SOLO 40000
#define CH_DUO  20000

__device__ __forceinline__ float edge_energy(float d, float qi, float qj,
                                             float di, float dj) {
    float inv_d   = __frcp_rn(d);
    float dsh     = __fsqrt_rn(fmaf(d, d, 1.0f));
    float inv_dsh = __frcp_rn(dsh);
    float x  = d * (1.0f / CUTOFF_SR_C);
    float x3 = x * x * x;
    float sw = fmaf(x3, fmaf(x, fmaf(x, -6.0f, 15.0f), -10.0f), 1.0f);
    float sw_off = (d < CUTOFF_SR_C) ? sw : 0.0f;
    float Eoq = inv_d   + fmaf(d,   (1.0f / CUTOFF_SQ_C), -(2.0f / CUTOFF_C));
    float Esq = inv_dsh + fmaf(dsh, (1.0f / CUTOFF_SQ_C), -(2.0f / CUTOFF_C));
    float Eq  = (KEHALF_C * qi * qj) * fmaf(sw_off, Esq - Eoq, Eoq);
    float Eod = inv_d * inv_d * inv_d;
    float Esd = inv_dsh * inv_dsh * inv_dsh;
    float Ed  = (KEHALF_C * di * dj) * fmaf(sw_off, Esd - Eod, Eod);
    return Eq + Ed;
}

__device__ __forceinline__ unsigned h2bits(__half2 h) {
    union { __half2 h; unsigned u; } c; c.h = h; return c.u;
}
__device__ __forceinline__ __half2 bits2h(unsigned u) {
    union { unsigned u; __half2 h; } c; c.u = u; return c.h;
}
// half2 atomic add (LDS): HW atomicAdd(__half2*) (ds_pk_add_f16) if available.
template <typename T>
__device__ __forceinline__ auto atom_add_h2(T* p, T v, int)
    -> decltype(atomicAdd(p, v), void()) {
    atomicAdd(p, v);
}
template <typename T>
__device__ __forceinline__ void atom_add_h2(T* p, T v, long) {
    unsigned* u = (unsigned*)p;
    unsigned old = *u, assumed;
    do {
        assumed = old;
        __half2 sum = __hadd2(bits2h(assumed), v);
        old = atomicCAS(u, assumed, h2bits(sum));
    } while (old != assumed);
}

// Fast-exact per-edge radial factors via HW rcp/rsq (errors << fp16 rounding).
// Returns half2{qj*F, dipj*G} bit-pattern. Validity (d<=cutoff) handled by caller.
__device__ __forceinline__ unsigned vw_bits(float d, unsigned hqbits) {
    float inv_d   = __builtin_amdgcn_rcpf(d);
    float dsh2    = fmaf(d, d, 1.0f);
    float inv_dsh = __builtin_amdgcn_rsqf(dsh2);   // 1/sqrt(d^2+1)
    float dsh     = dsh2 * inv_dsh;                // sqrt(d^2+1)
    float x  = d * (1.0f / CUTOFF_SR_C);
    float x3 = x * x * x;
    float sw = fmaf(x3, fmaf(x, fmaf(x, -6.0f, 15.0f), -10.0f), 1.0f);
    float sw_off = (d < CUTOFF_SR_C) ? sw : 0.0f;
    float Foq = inv_d   + fmaf(d,   (1.0f / CUTOFF_SQ_C), -(2.0f / CUTOFF_C));
    float Fsq = inv_dsh + fmaf(dsh, (1.0f / CUTOFF_SQ_C), -(2.0f / CUTOFF_C));
    float F   = fmaf(sw_off, Fsq - Foq, Foq);
    float God = inv_d * inv_d * inv_d;
    float Gsd = inv_dsh * inv_dsh * inv_dsh;
    float G   = fmaf(sw_off, Gsd - God, God);
    float2 q2 = __half22float2(bits2h(hqbits));
    __half2 vw = __floats2half2_rn((KEHALF_C * q2.x) * F, (KEHALF_C * q2.y) * G);
    return h2bits(vw);
}

// Pack {q, dip} -> half2 (4 B / atom), j-side gather table.
__global__ __launch_bounds__(256) void pc_pack_qd_h(
    const float* __restrict__ q,
    const float* __restrict__ dip,
    __half2*     __restrict__ qd,
    int n_atoms)
{
    int a = blockIdx.x * 256 + threadIdx.x;
    if (a < n_atoms) qd[a] = __floats2half2_rn(q[a], dip[a]);
}

// ---------------- PASS A: per-edge vw precompute (2-group batch) ------------
// Emits ONLY vw = half2{qj*F, dipj*G} per edge (4 B). Out-of-cutoff -> vw=0.
// Gathers are MASKED by validity (d<=cutoff): ~11% fewer L1/L2 line fetches.
__global__ __launch_bounds__(256) void pc_edge_vw(
    const float*   __restrict__ dist,
    const int*     __restrict__ idx_j,
    const __half2* __restrict__ qd,
    uint4*         __restrict__ vwo,     // [n4] groups of 4 edges
    unsigned*      __restrict__ vws,     // scalar view (tail records)
    int n_edges, int n4, int half)
{
    const int t = blockIdx.x * 256 + (int)threadIdx.x;
    const int4*   j4p = (const int4*)idx_j;
    const float4* d4p = (const float4*)dist;
    const __half2 hzero = __floats2half2_rn(0.0f, 0.0f);

    if (t < half) {
        const int  ga = t;
        const int  gb = t + half;
        const bool vb = gb < n4;
        const int  gbs = vb ? gb : ga;    // safe addr, cndmask not branch

        int4   ja = j4p[ga];
        int4   jb = j4p[gbs];
        float4 da = d4p[ga];
        float4 db = d4p[gbs];

        bool va0 = da.x <= CUTOFF_C, va1 = da.y <= CUTOFF_C;
        bool va2 = da.z <= CUTOFF_C, va3 = da.w <= CUTOFF_C;
        bool vb0 = db.x <= CUTOFF_C, vb1 = db.y <= CUTOFF_C;
        bool vb2 = db.z <= CUTOFF_C, vb3 = db.w <= CUTOFF_C;

        __half2 q0 = va0 ? qd[ja.x] : hzero;
        __half2 q1 = va1 ? qd[ja.y] : hzero;
        __half2 q2 = va2 ? qd[ja.z] : hzero;
        __half2 q3 = va3 ? qd[ja.w] : hzero;
        __half2 q4 = vb0 ? qd[jb.x] : hzero;
        __half2 q5 = vb1 ? qd[jb.y] : hzero;
        __half2 q6 = vb2 ? qd[jb.z] : hzero;
        __half2 q7 = vb3 ? qd[jb.w] : hzero;

        unsigned w0 = vw_bits(da.x, h2bits(q0));
        unsigned w1 = vw_bits(da.y, h2bits(q1));
        unsigned w2 = vw_bits(da.z, h2bits(q2));
        unsigned w3 = vw_bits(da.w, h2bits(q3));
        unsigned w4 = vw_bits(db.x, h2bits(q4));
        unsigned w5 = vw_bits(db.y, h2bits(q5));
        unsigned w6 = vw_bits(db.z, h2bits(q6));
        unsigned w7 = vw_bits(db.w, h2bits(q7));

        w0 = va0 ? w0 : 0u;  w1 = va1 ? w1 : 0u;
        w2 = va2 ? w2 : 0u;  w3 = va3 ? w3 : 0u;
        w4 = vb0 ? w4 : 0u;  w5 = vb1 ? w5 : 0u;
        w6 = vb2 ? w6 : 0u;  w7 = vb3 ? w7 : 0u;

        vwo[ga] = make_uint4(w0, w1, w2, w3);
        if (vb) vwo[gb] = make_uint4(w4, w5, w6, w7);
    }

    // scalar tail (n_edges % 4)
    const int tl = n_edges & 3;
    if (blockIdx.x == 0 && (int)threadIdx.x < tl) {
        int e = (n4 << 2) + (int)threadIdx.x;
        float d = dist[e];
        bool  v = d <= CUTOFF_C;
        __half2 hq = v ? qd[idx_j[e]] : hzero;
        unsigned w = vw_bits(d, h2bits(hq));
        vws[e] = v ? w : 0u;
    }
}

// ---------------- PASS B: vw scatter (8-edge unrolled, CH-templated) --------
// Visits = nch * n_edges; SOLO (CH=40000, nch=3) cuts visits 40% vs DUO.
// Block b: s = b % S (edge slice), c = b / S (atom chunk). S % 8 == 0 keeps
// same-slice blocks on one XCD so the nch chunk re-reads hit L2.
template <int CH, int BLK>
__global__ __launch_bounds__(BLK) void pc_scatter_vw(
    const int*      __restrict__ idx_i,
    const unsigned* __restrict__ vw,
    __half2*        __restrict__ partial,   // [S][n_atoms] half2 {sumv,sumw}
    int n_edges, int n4, int S, int gps, int n_atoms)
{
    extern __shared__ char smem[];
    __half2* acc2 = (__half2*)smem;                                  // CH

    const int s = blockIdx.x % S;
    const int c = blockIdx.x / S;
    const unsigned base = (unsigned)(c * CH);
    const int lim = min(CH, n_atoms - (int)base);

    // vectorized LDS zero-init (CH % 4 == 0)
    {
        uint4* z4 = (uint4*)acc2;
        const uint4 z = make_uint4(0u, 0u, 0u, 0u);
        for (int i = threadIdx.x; i < CH / 4; i += BLK) z4[i] = z;
    }
    __syncthreads();

    const int4*  i4p = (const int4*)idx_i;
    const uint4* v4p = (const uint4*)vw;
    const int g0 = s * gps;
    const int g1 = min(g0 + gps, n4);
    for (int g = g0 + (int)threadIdx.x; g < g1; g += 2 * BLK) {
        const int  gB   = g + BLK;
        const bool hasB = gB < g1;
        const int  gBs  = hasB ? gB : g;

        int4  iA = i4p[g];
        int4  iB = i4p[gBs];
        uint4 vA = v4p[g];
        uint4 vB = v4p[gBs];

        unsigned a0 = (unsigned)iA.x - base;
        unsigned a1 = (unsigned)iA.y - base;
        unsigned a2 = (unsigned)iA.z - base;
        unsigned a3 = (unsigned)iA.w - base;
        if (a0 < (unsigned)CH) atom_add_h2(&acc2[a0], bits2h(vA.x), 0);
        if (a1 < (unsigned)CH) atom_add_h2(&acc2[a1], bits2h(vA.y), 0);
        if (a2 < (unsigned)CH) atom_add_h2(&acc2[a2], bits2h(vA.z), 0);
        if (a3 < (unsigned)CH) atom_add_h2(&acc2[a3], bits2h(vA.w), 0);
        if (hasB) {
            unsigned b0 = (unsigned)iB.x - base;
            unsigned b1 = (unsigned)iB.y - base;
            unsigned b2 = (unsigned)iB.z - base;
            unsigned b3 = (unsigned)iB.w - base;
            if (b0 < (unsigned)CH) atom_add_h2(&acc2[b0], bits2h(vB.x), 0);
            if (b1 < (unsigned)CH) atom_add_h2(&acc2[b1], bits2h(vB.y), 0);
            if (b2 < (unsigned)CH) atom_add_h2(&acc2[b2], bits2h(vB.z), 0);
            if (b3 < (unsigned)CH) atom_add_h2(&acc2[b3], bits2h(vB.w), 0);
        }
    }

    if (s == S - 1) {  // scalar tail (n_edges % 4)
        for (int e = (n4 << 2) + (int)threadIdx.x; e < n_edges; e += BLK) {
            unsigned lc = (unsigned)idx_i[e] - base;
            if (lc < (unsigned)CH) atom_add_h2(&acc2[lc], bits2h(vw[e]), 0);
        }
    }

    __syncthreads();
    // vectorized writeback: partial rows are 16B-aligned when n_atoms*4 and
    // base*4 are multiples of 16 (n_atoms%4==0, CH%4==0); fallback scalar else.
    __half2* row = partial + (size_t)s * n_atoms + (int)base;
    if (((n_atoms & 3) == 0) && (lim & 3) == 0) {
        uint4* r4 = (uint4*)row;
        const uint4* a4 = (const uint4*)acc2;
        for (int i = threadIdx.x; i < lim / 4; i += BLK) r4[i] = a4[i];
    } else {
        for (int i = threadIdx.x; i < lim; i += BLK) row[i] = acc2[i];
    }
}

// out[a] = q[a]*sum_s(v) + dip[a]*sum_s(w) — exact fp32 recombination.
// Requires S % 4 == 0.
__global__ __launch_bounds__(256) void pc_reduce_vw(
    const __half2* __restrict__ partial,   // [S][n_atoms]
    const float*   __restrict__ q,
    const float*   __restrict__ dip,
    float*         __restrict__ out,
    int n_atoms, int S)
{
    __shared__ float2 sh[256];
    int a0   = blockIdx.x * 64;
    int lane = threadIdx.x & 63;
    int w    = threadIdx.x >> 6;
    int a    = a0 + lane;

    float sv = 0.0f, sw = 0.0f;
    if (a < n_atoms) {
        int per = S >> 2;                  // S % 4 == 0
        const __half2* p = partial + a;
        int s = w * per, send = s + per;
        for (; s < send; ++s) {
            float2 t = __half22float2(p[(size_t)s * n_atoms]);
            sv += t.x; sw += t.y;
        }
    }
    sh[threadIdx.x] = make_float2(sv, sw);
    __syncthreads();
    if (w == 0 && a < n_atoms) {
        float2 t0 = sh[lane],       t1 = sh[64 + lane];
        float2 t2 = sh[128 + lane], t3 = sh[192 + lane];
        float fv = (t0.x + t1.x) + (t2.x + t3.x);
        float fw = (t0.y + t1.y) + (t2.y + t3.y);
        out[a] = fmaf(q[a], fv, dip[a] * fw);
    }
}

// Full-precision global-atomic fallback (probe failure / tiny ws).
__global__ __launch_bounds__(256) void pc_dipole_edges_atomic(
    const float* __restrict__ q,
    const float* __restrict__ dip,
    const float* __restrict__ dist,
    const int*   __restrict__ idx_i,
    const int*   __restrict__ idx_j,
    float*       __restrict__ out,
    int n_edges)
{
    int t = blockIdx.x * blockDim.x + threadIdx.x;
    const int stride = gridDim.x * blockDim.x;
    for (int e = t; e < n_edges; e += stride) {
        float d = dist[e];
        if (d > CUTOFF_C) continue;
        int i = idx_i[e], j = idx_j[e];
        atomicAdd(&out[i], edge_energy(d, q[i], q[j], dip[i], dip[j]));
    }
}

static int probe_blocks(const void* f, int blk, size_t lds) {
    hipError_t e1 = hipFuncSetAttribute(
        f, hipFuncAttributeMaxDynamicSharedMemorySize, (int)lds);
    int nb = 0;
    hipError_t e2 = hipOccupancyMaxActiveBlocksPerMultiprocessor(&nb, f, blk, lds);
    if (e1 != hipSuccess || e2 != hipSuccess) return 0;
    return nb;
}

extern "C" void kernel_launch(void* const* d_in, const int* in_sizes, int n_in,
                              void* d_out, int out_size, void* d_ws, size_t ws_size,
                              hipStream_t stream) {
    const float* q     = (const float*)d_in[0];
    const float* dip   = (const float*)d_in[1];
    const float* dist  = (const float*)d_in[2];
    const int*   idx_i = (const int*)d_in[3];
    const int*   idx_j = (const int*)d_in[4];
    float*       out   = (float*)d_out;

    int n_edges = in_sizes[2];
    int n_atoms = out_size;
    int n4      = n_edges >> 2;
    int half    = (n4 + 1) >> 1;

    size_t qd_b = ((size_t)n_atoms * sizeof(__half2) + 255) & ~(size_t)255;
    size_t vw_b = (((size_t)n_edges * 4) + 255) & ~(size_t)255;

    // ---- scatter config select: SOLO (nch=3, fewer visits) else DUO ----
    size_t lds_solo = (size_t)CH_SOLO * sizeof(__half2);   // 160000 B
    size_t lds_duo  = (size_t)CH_DUO  * sizeof(__half2);   //  80000 B
    int nb_solo = probe_blocks((const void*)&pc_scatter_vw<CH_SOLO, BLK1>,
                               BLK1, lds_solo);
    int nb_duo  = probe_blocks((const void*)&pc_scatter_vw<CH_DUO, BLK1>,
                               BLK1, lds_duo);

    bool   use_solo = (nb_solo >= 1);
    int    CH  = use_solo ? CH_SOLO : CH_DUO;
    size_t lds = use_solo ? lds_solo : lds_duo;
    int    cap = use_solo ? 256 : 512;          // blocks resident device-wide

    int S_new = 0, nch = 0;
    bool scatter_ok = (use_solo || nb_duo >= 2);
    if (scatter_ok && n_atoms > 0 && n4 > 0 && ws_size > qd_b + vw_b) {
        nch = (n_atoms + CH - 1) / CH;          // 3 (solo) / 5 (duo) @100K
        S_new = (cap / nch) & ~7;               // 80 (solo) / 96 (duo)
        size_t avail = ws_size - qd_b - vw_b;
        int S_fit = (int)(avail / ((size_t)n_atoms * sizeof(__half2))) & ~7;
        if (S_fit < S_new) S_new = S_fit;
    }

    if (S_new >= 8) {
        __half2*  qd      = (__half2*)d_ws;
        unsigned* vw      = (unsigned*)((char*)d_ws + qd_b);
        __half2*  partial = (__half2*)((char*)d_ws + qd_b + vw_b);
        int       gps     = (n4 + S_new - 1) / S_new;
        int       gridA   = (half + 255) / 256;
        if (gridA < 1) gridA = 1;

        pc_pack_qd_h<<<(n_atoms + 255) / 256, 256, 0, stream>>>(q, dip, qd,
                                                                n_atoms);
        pc_edge_vw<<<gridA, 256, 0, stream>>>(dist, idx_j, qd,
                                              (uint4*)vw, vw,
                                              n_edges, n4, half);
        if (use_solo)
            pc_scatter_vw<CH_SOLO, BLK1>
                <<<S_new * nch, BLK1, lds, stream>>>(
                    idx_i, vw, partial, n_edges, n4, S_new, gps, n_atoms);
        else
            pc_scatter_vw<CH_DUO, BLK1>
                <<<S_new * nch, BLK1, lds, stream>>>(
                    idx_i, vw, partial, n_edges, n4, S_new, gps, n_atoms);
        pc_reduce_vw<<<(n_atoms + 63) / 64, 256, 0, stream>>>(
            partial, q, dip, out, n_atoms, S_new);
        return;
    }

    // ---------- full-precision atomic fallback ----------
    hipMemsetAsync(out, 0, (size_t)n_atoms * sizeof(float), stream);
    int grid = (n_edges + 255) / 256;
    if (grid < 1) grid = 1;
    pc_dipole_edges_atomic<<<grid, 256, 0, stream>>>(
        q, dip, dist, idx_i, idx_j, out, n_edges);
}

// Round 8
// 152.478 us; speedup vs baseline: 3.8390x; 1.1022x over previous
//
#include <hip/hip_runtime.h>
#include <hip/hip_bf16.h>
#include <hip/hip_fp16.h>

// Problem constants (match reference)
#define CUTOFF_C    12.0f
#define CUTOFF_SR_C 2.0f
#define CUTOFF_SQ_C 144.0f
#define KEHALF_C    7.199822675975274f

#define BLK1   1024

// Fused gather+compute+scatter configs (no LUT, exact math):
// DUO : CH=20000 -> 80000 B LDS, 2 blocks/CU, nch=5 @100K, 32M visits.
// SOLO: CH=40000 -> 160000 B LDS, 1 block/CU, nch=3 (fallback if duo probe fails).
#define CH_DUO  20000
#define CH_SOLO 40000

__device__ __forceinline__ float edge_energy(float d, float qi, float qj,
                                             float di, float dj) {
    float inv_d   = __frcp_rn(d);
    float dsh     = __fsqrt_rn(fmaf(d, d, 1.0f));
    float inv_dsh = __frcp_rn(dsh);
    float x  = d * (1.0f / CUTOFF_SR_C);
    float x3 = x * x * x;
    float sw = fmaf(x3, fmaf(x, fmaf(x, -6.0f, 15.0f), -10.0f), 1.0f);
    float sw_off = (d < CUTOFF_SR_C) ? sw : 0.0f;
    float Eoq = inv_d   + fmaf(d,   (1.0f / CUTOFF_SQ_C), -(2.0f / CUTOFF_C));
    float Esq = inv_dsh + fmaf(dsh, (1.0f / CUTOFF_SQ_C), -(2.0f / CUTOFF_C));
    float Eq  = (KEHALF_C * qi * qj) * fmaf(sw_off, Esq - Eoq, Eoq);
    float Eod = inv_d * inv_d * inv_d;
    float Esd = inv_dsh * inv_dsh * inv_dsh;
    float Ed  = (KEHALF_C * di * dj) * fmaf(sw_off, Esd - Eod, Eod);
    return Eq + Ed;
}

__device__ __forceinline__ unsigned h2bits(__half2 h) {
    union { __half2 h; unsigned u; } c; c.h = h; return c.u;
}
__device__ __forceinline__ __half2 bits2h(unsigned u) {
    union { unsigned u; __half2 h; } c; c.u = u; return c.h;
}
// half2 atomic add (LDS): HW atomicAdd(__half2*) (ds_pk_add_f16) if available.
template <typename T>
__device__ __forceinline__ auto atom_add_h2(T* p, T v, int)
    -> decltype(atomicAdd(p, v), void()) {
    atomicAdd(p, v);
}
template <typename T>
__device__ __forceinline__ void atom_add_h2(T* p, T v, long) {
    unsigned* u = (unsigned*)p;
    unsigned old = *u, assumed;
    do {
        assumed = old;
        __half2 sum = __hadd2(bits2h(assumed), v);
        old = atomicCAS(u, assumed, h2bits(sum));
    } while (old != assumed);
}

// Fast-exact per-edge radial factors via HW rcp/rsq (errors << fp16 rounding).
// Returns half2{qj*F, dipj*G} bit-pattern. Validity handled by caller.
__device__ __forceinline__ unsigned vw_bits(float d, unsigned hqbits) {
    float inv_d   = __builtin_amdgcn_rcpf(d);
    float dsh2    = fmaf(d, d, 1.0f);
    float inv_dsh = __builtin_amdgcn_rsqf(dsh2);   // 1/sqrt(d^2+1)
    float dsh     = dsh2 * inv_dsh;                // sqrt(d^2+1)
    float x  = d * (1.0f / CUTOFF_SR_C);
    float x3 = x * x * x;
    float sw = fmaf(x3, fmaf(x, fmaf(x, -6.0f, 15.0f), -10.0f), 1.0f);
    float sw_off = (d < CUTOFF_SR_C) ? sw : 0.0f;
    float Foq = inv_d   + fmaf(d,   (1.0f / CUTOFF_SQ_C), -(2.0f / CUTOFF_C));
    float Fsq = inv_dsh + fmaf(dsh, (1.0f / CUTOFF_SQ_C), -(2.0f / CUTOFF_C));
    float F   = fmaf(sw_off, Fsq - Foq, Foq);
    float God = inv_d * inv_d * inv_d;
    float Gsd = inv_dsh * inv_dsh * inv_dsh;
    float G   = fmaf(sw_off, Gsd - God, God);
    float2 q2 = __half22float2(bits2h(hqbits));
    __half2 vw = __floats2half2_rn((KEHALF_C * q2.x) * F, (KEHALF_C * q2.y) * G);
    return h2bits(vw);
}

// Pack {q, dip} -> half2 (4 B / atom), j-side gather table.
__global__ __launch_bounds__(256) void pc_pack_qd_h(
    const float* __restrict__ q,
    const float* __restrict__ dip,
    __half2*     __restrict__ qd,
    int n_atoms)
{
    int a = blockIdx.x * 256 + threadIdx.x;
    if (a < n_atoms) qd[a] = __floats2half2_rn(q[a], dip[a]);
}

// ---------------- FUSED gather+compute+scatter (exact math, no LUT) ---------
// R0 measured fused(nch=6,LUT) = 72us == split edge+scatter (44+30) while
// saving a dispatch boundary. This version: nch=5 (CH=20000, -17% visits),
// exact rcp/rsq math (no LUT LDS reads -> no bank conflicts), 2-group unroll.
// Block b: s = b % S (edge slice), c = b / S (atom chunk). S % 8 == 0 keeps
// same-slice blocks on one XCD so the nch stream re-reads hit L2.
template <int CH, int BLK>
__global__ __launch_bounds__(BLK) void pc_fused_sc(
    const float*   __restrict__ dist,
    const int*     __restrict__ idx_i,
    const int*     __restrict__ idx_j,
    const __half2* __restrict__ qd,
    __half2*       __restrict__ partial,   // [S][n_atoms] half2 {sumv,sumw}
    int n_edges, int n4, int S, int gps, int n_atoms)
{
    extern __shared__ char smem[];
    __half2* acc2 = (__half2*)smem;                                  // CH

    const int s = blockIdx.x % S;
    const int c = blockIdx.x / S;
    const unsigned base = (unsigned)(c * CH);
    const int lim = min(CH, n_atoms - (int)base);

    // vectorized LDS zero-init (CH % 4 == 0)
    {
        uint4* z4 = (uint4*)acc2;
        const uint4 z = make_uint4(0u, 0u, 0u, 0u);
        for (int i = threadIdx.x; i < CH / 4; i += BLK) z4[i] = z;
    }
    __syncthreads();

    const int4*   i4p = (const int4*)idx_i;
    const int4*   j4p = (const int4*)idx_j;
    const float4* d4p = (const float4*)dist;
    const __half2 hzero = __floats2half2_rn(0.0f, 0.0f);

    const int g0 = s * gps;
    const int g1 = min(g0 + gps, n4);
    for (int g = g0 + (int)threadIdx.x; g < g1; g += 2 * BLK) {
        const int  gB   = g + BLK;
        const bool hasB = gB < g1;
        const int  gBs  = hasB ? gB : g;

        int4   iA = i4p[g];
        int4   iB = i4p[gBs];
        int4   jA = j4p[g];
        int4   jB = j4p[gBs];
        float4 dA = d4p[g];
        float4 dB = d4p[gBs];

        unsigned a0 = (unsigned)iA.x - base;
        unsigned a1 = (unsigned)iA.y - base;
        unsigned a2 = (unsigned)iA.z - base;
        unsigned a3 = (unsigned)iA.w - base;
        unsigned b0 = (unsigned)iB.x - base;
        unsigned b1 = (unsigned)iB.y - base;
        unsigned b2 = (unsigned)iB.z - base;
        unsigned b3 = (unsigned)iB.w - base;

        bool vA0 = (a0 < (unsigned)CH) && (dA.x <= CUTOFF_C);
        bool vA1 = (a1 < (unsigned)CH) && (dA.y <= CUTOFF_C);
        bool vA2 = (a2 < (unsigned)CH) && (dA.z <= CUTOFF_C);
        bool vA3 = (a3 < (unsigned)CH) && (dA.w <= CUTOFF_C);
        bool vB0 = hasB && (b0 < (unsigned)CH) && (dB.x <= CUTOFF_C);
        bool vB1 = hasB && (b1 < (unsigned)CH) && (dB.y <= CUTOFF_C);
        bool vB2 = hasB && (b2 < (unsigned)CH) && (dB.z <= CUTOFF_C);
        bool vB3 = hasB && (b3 < (unsigned)CH) && (dB.w <= CUTOFF_C);

        // masked gathers (only owning chunk + in-cutoff pulls a line)
        __half2 q0 = vA0 ? qd[jA.x] : hzero;
        __half2 q1 = vA1 ? qd[jA.y] : hzero;
        __half2 q2 = vA2 ? qd[jA.z] : hzero;
        __half2 q3 = vA3 ? qd[jA.w] : hzero;
        __half2 q4 = vB0 ? qd[jB.x] : hzero;
        __half2 q5 = vB1 ? qd[jB.y] : hzero;
        __half2 q6 = vB2 ? qd[jB.z] : hzero;
        __half2 q7 = vB3 ? qd[jB.w] : hzero;

        if (vA0) atom_add_h2(&acc2[a0], bits2h(vw_bits(dA.x, h2bits(q0))), 0);
        if (vA1) atom_add_h2(&acc2[a1], bits2h(vw_bits(dA.y, h2bits(q1))), 0);
        if (vA2) atom_add_h2(&acc2[a2], bits2h(vw_bits(dA.z, h2bits(q2))), 0);
        if (vA3) atom_add_h2(&acc2[a3], bits2h(vw_bits(dA.w, h2bits(q3))), 0);
        if (vB0) atom_add_h2(&acc2[b0], bits2h(vw_bits(dB.x, h2bits(q4))), 0);
        if (vB1) atom_add_h2(&acc2[b1], bits2h(vw_bits(dB.y, h2bits(q5))), 0);
        if (vB2) atom_add_h2(&acc2[b2], bits2h(vw_bits(dB.z, h2bits(q6))), 0);
        if (vB3) atom_add_h2(&acc2[b3], bits2h(vw_bits(dB.w, h2bits(q7))), 0);
    }

    if (s == S - 1) {  // scalar tail (n_edges % 4)
        for (int e = (n4 << 2) + (int)threadIdx.x; e < n_edges; e += BLK) {
            unsigned lc = (unsigned)idx_i[e] - base;
            float d = dist[e];
            if (lc < (unsigned)CH && d <= CUTOFF_C) {
                unsigned w = vw_bits(d, h2bits(qd[idx_j[e]]));
                atom_add_h2(&acc2[lc], bits2h(w), 0);
            }
        }
    }

    __syncthreads();
    __half2* row = partial + (size_t)s * n_atoms + (int)base;
    if (((n_atoms & 3) == 0) && (lim & 3) == 0) {
        uint4* r4 = (uint4*)row;
        const uint4* a4 = (const uint4*)acc2;
        for (int i = threadIdx.x; i < lim / 4; i += BLK) r4[i] = a4[i];
    } else {
        for (int i = threadIdx.x; i < lim; i += BLK) row[i] = acc2[i];
    }
}

// out[a] = q[a]*sum_s(v) + dip[a]*sum_s(w) — exact fp32 recombination.
// Requires S % 4 == 0.
__global__ __launch_bounds__(256) void pc_reduce_vw(
    const __half2* __restrict__ partial,   // [S][n_atoms]
    const float*   __restrict__ q,
    const float*   __restrict__ dip,
    float*         __restrict__ out,
    int n_atoms, int S)
{
    __shared__ float2 sh[256];
    int a0   = blockIdx.x * 64;
    int lane = threadIdx.x & 63;
    int w    = threadIdx.x >> 6;
    int a    = a0 + lane;

    float sv = 0.0f, sw = 0.0f;
    if (a < n_atoms) {
        int per = S >> 2;                  // S % 4 == 0
        const __half2* p = partial + a;
        int s = w * per, send = s + per;
        for (; s < send; ++s) {
            float2 t = __half22float2(p[(size_t)s * n_atoms]);
            sv += t.x; sw += t.y;
        }
    }
    sh[threadIdx.x] = make_float2(sv, sw);
    __syncthreads();
    if (w == 0 && a < n_atoms) {
        float2 t0 = sh[lane],       t1 = sh[64 + lane];
        float2 t2 = sh[128 + lane], t3 = sh[192 + lane];
        float fv = (t0.x + t1.x) + (t2.x + t3.x);
        float fw = (t0.y + t1.y) + (t2.y + t3.y);
        out[a] = fmaf(q[a], fv, dip[a] * fw);
    }
}

// Full-precision global-atomic fallback (probe failure / tiny ws).
__global__ __launch_bounds__(256) void pc_dipole_edges_atomic(
    const float* __restrict__ q,
    const float* __restrict__ dip,
    const float* __restrict__ dist,
    const int*   __restrict__ idx_i,
    const int*   __restrict__ idx_j,
    float*       __restrict__ out,
    int n_edges)
{
    int t = blockIdx.x * blockDim.x + threadIdx.x;
    const int stride = gridDim.x * blockDim.x;
    for (int e = t; e < n_edges; e += stride) {
        float d = dist[e];
        if (d > CUTOFF_C) continue;
        int i = idx_i[e], j = idx_j[e];
        atomicAdd(&out[i], edge_energy(d, q[i], q[j], dip[i], dip[j]));
    }
}

static int probe_blocks(const void* f, int blk, size_t lds) {
    hipError_t e1 = hipFuncSetAttribute(
        f, hipFuncAttributeMaxDynamicSharedMemorySize, (int)lds);
    int nb = 0;
    hipError_t e2 = hipOccupancyMaxActiveBlocksPerMultiprocessor(&nb, f, blk, lds);
    if (e1 != hipSuccess || e2 != hipSuccess) return 0;
    return nb;
}

extern "C" void kernel_launch(void* const* d_in, const int* in_sizes, int n_in,
                              void* d_out, int out_size, void* d_ws, size_t ws_size,
                              hipStream_t stream) {
    const float* q     = (const float*)d_in[0];
    const float* dip   = (const float*)d_in[1];
    const float* dist  = (const float*)d_in[2];
    const int*   idx_i = (const int*)d_in[3];
    const int*   idx_j = (const int*)d_in[4];
    float*       out   = (float*)d_out;

    int n_edges = in_sizes[2];
    int n_atoms = out_size;
    int n4      = n_edges >> 2;

    size_t qd_b = ((size_t)n_atoms * sizeof(__half2) + 255) & ~(size_t)255;

    // ---- fused config select: DUO (2 blocks/CU, 32 waves) preferred ----
    size_t lds_duo  = (size_t)CH_DUO  * sizeof(__half2);   //  80000 B
    size_t lds_solo = (size_t)CH_SOLO * sizeof(__half2);   // 160000 B
    int nb_duo  = probe_blocks((const void*)&pc_fused_sc<CH_DUO, BLK1>,
                               BLK1, lds_duo);
    int nb_solo = probe_blocks((const void*)&pc_fused_sc<CH_SOLO, BLK1>,
                               BLK1, lds_solo);

    bool   use_duo = (nb_duo >= 2);
    int    CH  = use_duo ? CH_DUO : CH_SOLO;
    size_t lds = use_duo ? lds_duo : lds_solo;
    int    cap = use_duo ? 512 : 256;           // resident blocks device-wide

    int S = 0, nch = 0;
    bool ok = (use_duo || nb_solo >= 1);
    if (ok && n_atoms > 0 && n4 > 0 && ws_size > qd_b) {
        nch = (n_atoms + CH - 1) / CH;          // 5 (duo) / 3 (solo) @100K
        S = (cap / nch) & ~7;                   // 96 (duo) / 80 (solo)
        size_t avail = ws_size - qd_b;
        int S_fit = (int)(avail / ((size_t)n_atoms * sizeof(__half2))) & ~7;
        if (S_fit < S) S = S_fit;
    }

    if (S >= 8) {
        __half2* qd      = (__half2*)d_ws;
        __half2* partial = (__half2*)((char*)d_ws + qd_b);
        int      gps     = (n4 + S - 1) / S;

        pc_pack_qd_h<<<(n_atoms + 255) / 256, 256, 0, stream>>>(q, dip, qd,
                                                                n_atoms);
        if (use_duo)
            pc_fused_sc<CH_DUO, BLK1>
                <<<S * nch, BLK1, lds, stream>>>(
                    dist, idx_i, idx_j, qd, partial, n_edges, n4, S, gps,
                    n_atoms);
        else
            pc_fused_sc<CH_SOLO, BLK1>
                <<<S * nch, BLK1, lds, stream>>>(
                    dist, idx_i, idx_j, qd, partial, n_edges, n4, S, gps,
                    n_atoms);
        pc_reduce_vw<<<(n_atoms + 63) / 64, 256, 0, stream>>>(
            partial, q, dip, out, n_atoms, S);
        return;
    }

    // ---------- full-precision atomic fallback ----------
    hipMemsetAsync(out, 0, (size_t)n_atoms * sizeof(float), stream);
    int grid = (n_edges + 255) / 256;
    if (grid < 1) grid = 1;
    pc_dipole_edges_atomic<<<grid, 256, 0, stream>>>(
        q, dip, dist, idx_i, idx_j, out, n_edges);
}